// Round 3
// baseline (237.361 us; speedup 1.0000x reference)
//
#include <hip/hip_runtime.h>

// Izhikevich spiking neuron scan — float4-vectorized, time-chunked.
// x: [T=512, N=65536] f32. out: [T, N] f32 spike train (0.0 / 1.0).
//
// Per neuron: v = (4v^2+5v+1.4-r+x_t)*DT ; r = 0.02*(0.2v-v)*DT (new v);
//             fire = v>=0.3 -> v=-0.065, r+=0.008 ; out_t = fire.
//
// Design (R3):
//  * float4 loads/stores: 16 B/lane, 4x fewer mem instructions than R2's
//    scalar dwords (R2 stuck at 2.5 TB/s = instruction-rate bound; the
//    harness's own fill kernel shows 6.6 TB/s is reachable).
//  * 4 neurons/thread: 4 independent recurrence chains -> 4x ILP hides the
//    dependent-FMA latency of the serial per-neuron update.
//  * Time-split (16 chunks of 32 + 8 warmup steps): contraction factor
//    ~(5/512)/step makes 8 warmup steps shrink seed error ~1e-16x, below
//    fp32 ulp; output bit (v>=0.3, |v|<=~0.015) has ~20x margin anyway.
//    -> grid 64x16 = 1024 blocks = 4 blocks/CU = 16 waves/CU.

#define T_STEPS 512
#define N_NEUR  65536
#define NV      (N_NEUR / 4)     // float4 columns per timestep = 16384
#define DT      (1.0f / 512.0f)
#define TCH     32               // timesteps written per chunk
#define WARM    8                // warmup steps for chunk-seed convergence

__device__ __forceinline__ float izi_step(float xt, float& v, float& r) {
    v = (4.0f * v * v + 5.0f * v + 1.4f - r + xt) * DT;
    r = 0.02f * (0.2f * v - v) * DT;
    const bool fire = v >= 0.3f;
    if (fire) { v = -0.065f; r += 0.008f; }
    return fire ? 1.0f : 0.0f;
}

__global__ __launch_bounds__(256, 4) void izi_kernel(const float* __restrict__ x,
                                                     float* __restrict__ out) {
    const int g = blockIdx.x * 256 + threadIdx.x;   // float4-column, coalesced
    const int c = blockIdx.y;                       // time chunk 0..15
    const int tstart = c * TCH;

    const float4* xp = (const float4*)x + g;
    float4*       op = (float4*)out + g;

    float4 v = make_float4(-0.065f, -0.065f, -0.065f, -0.065f);
    float4 r = make_float4(0.0f, 0.0f, 0.0f, 0.0f);

    if (c > 0) {
        #pragma unroll
        for (int t = tstart - WARM; t < tstart; ++t) {
            const float4 xt = xp[(size_t)t * NV];
            izi_step(xt.x, v.x, r.x);
            izi_step(xt.y, v.y, r.y);
            izi_step(xt.z, v.z, r.z);
            izi_step(xt.w, v.w, r.w);
        }
    }

    #pragma unroll 4
    for (int t = tstart; t < tstart + TCH; ++t) {
        const float4 xt = xp[(size_t)t * NV];
        float4 o;
        o.x = izi_step(xt.x, v.x, r.x);
        o.y = izi_step(xt.y, v.y, r.y);
        o.z = izi_step(xt.z, v.z, r.z);
        o.w = izi_step(xt.w, v.w, r.w);
        op[(size_t)t * NV] = o;
    }
}

extern "C" void kernel_launch(void* const* d_in, const int* in_sizes, int n_in,
                              void* d_out, int out_size, void* d_ws, size_t ws_size,
                              hipStream_t stream) {
    const float* x = (const float*)d_in[0];
    float* out = (float*)d_out;
    // grid: 16384 float4-cols / 256 threads = 64 blocks  x  16 time chunks.
    izi_kernel<<<dim3(NV / 256, T_STEPS / TCH), dim3(256), 0, stream>>>(x, out);
}